// Round 10
// baseline (4574.565 us; speedup 1.0000x reference)
//
#include <hip/hip_runtime.h>

// LSTM 2-layer fused persistent kernel — MFMA bf16 hi/lo pair-split, fp32 I/O.
// 256 blocks (1 batch row / CU) x 512 threads, __launch_bounds__(512,2) (the
// only proven no-spill regime: 128-VGPR grant).
// R10 change vs R9: TERM-MAJOR MFMA interleave. R9 counters: MfmaUtil 31.5%
// at 96 MFMA/SIMD/step = 15.75 cyc/MFMA == dependent-issue latency -> the
// acc-major order (3 back-to-back MFMAs into the same acc) serialized the
// matrix pipe. Now per k-slice: [ds_read b,al x6] [4x mfma(Ahi,bh)]
// [4x mfma(Ahi,bl)] [4x mfma(Alo,bh)] -> same-acc distance 4 (~19cyc > dep
// latency). Same reorder in proj phases B/D. xp[t] prefetched before the
// MFMA section (was a ~120cyc post-MFMA stall).
// Gate-major ownership (R9): wave w owns {i,f,g,o} x units [16w,16w+16);
// c-update wave-local via 4 __shfl; h ping-pong; 1 barrier/step.
// Fragment maps (m89-verified): A[row=lane&15, k=(lane>>4)*8+j],
// B[k=(lane>>4)*8+j, col=lane&15], D[col=lane&15, row=(lane>>4)*4+reg];
// B column-replicated -> every lane holds valid D rows.
// d_ws requirement: 917,504 B.

typedef __attribute__((ext_vector_type(8))) short bf16x8;
typedef __attribute__((ext_vector_type(4))) float f32x4;

#define NB   256
#define TSEQ 1024
#define II   64
#define HH   128
#define G4   512
#define TC   16
#define NCH  (TSEQ/TC)

// d_ws frag regions (16B units). idx = ((w*4+t)*NKS+s)*64 + lane.
#define F_WHH0_HI 0
#define F_WHH0_LO 8192
#define F_WHH1_HI 16384
#define F_WHH1_LO 24576
#define F_WIH1_HI 32768
#define F_WIH1_LO 40960
#define F_WIH0_HI 49152
#define F_WIH0_LO 53248
#define F_TOTAL   57344   // *16B = 917,504 B

#define KEEP4I(v) asm volatile("" : "+v"((v).x), "+v"((v).y), "+v"((v).z), "+v"((v).w))

__device__ __forceinline__ unsigned short f2bf(float f){
    unsigned u = __float_as_uint(f);
    unsigned r = u + 0x7FFFu + ((u >> 16) & 1u);
    return (unsigned short)(r >> 16);
}
__device__ __forceinline__ float bf2f(unsigned short h){
    return __uint_as_float(((unsigned)h) << 16);
}
__device__ __forceinline__ float tanh_f(float x){
    float ax = fabsf(x);
    float e  = __expf(2.f*ax);
    float t  = 1.f - 2.f/(e + 1.f);
    return copysignf(t, x);
}
__device__ __forceinline__ f32x4 mfma_(int4 a, bf16x8 b, f32x4 c){
    return __builtin_amdgcn_mfma_f32_16x16x32_bf16(
        __builtin_bit_cast(bf16x8, a), b, c, 0, 0, 0);
}

// ---------------- pack kernel: fp32 weights -> hi/lo bf16 A-fragments ------
// Gate-major row map: fragment (w, t4, s, lane) holds
// row = t4*128 + w*16 + (lane&15), k = s*32 + (lane>>4)*8 + j.
__global__ void pack_w(const float* __restrict__ Wih0, const float* __restrict__ Whh0,
                       const float* __restrict__ Wih1, const float* __restrict__ Whh1,
                       int4* __restrict__ ws)
{
    int fid = blockIdx.x * 256 + threadIdx.x;
    if (fid >= F_TOTAL) return;
    const float* src; int nks; bool lo; int rb;
    if (fid < F_WHH1_HI)      { src = Whh0; nks = 4; lo = fid >= F_WHH0_LO; rb = fid & 8191; }
    else if (fid < F_WIH1_HI) { src = Whh1; nks = 4; lo = fid >= F_WHH1_LO; rb = fid & 8191; }
    else if (fid < F_WIH0_HI) { src = Wih1; nks = 4; lo = fid >= F_WIH1_LO; rb = fid & 8191; }
    else                      { src = Wih0; nks = 2; lo = fid >= F_WIH0_LO; rb = (fid - F_WIH0_HI) & 4095; }
    int lane = rb & 63;
    int rem  = rb >> 6;
    int s    = rem % nks;
    int t    = (rem / nks) & 3;
    int w    = rem / (nks * 4);
    int row  = t * 128 + w * 16 + (lane & 15);   // gate-major
    int K    = nks * 32;
    int k0   = s * 32 + (lane >> 4) * 8;
    const float* p = src + (size_t)row * K + k0;
    unsigned short h[8];
    #pragma unroll
    for (int j = 0; j < 8; ++j){
        float v = p[j];
        unsigned short hi = f2bf(v);
        h[j] = lo ? f2bf(v - bf2f(hi)) : hi;
    }
    int4 o;
    o.x = (int)((unsigned)h[0] | ((unsigned)h[1] << 16));
    o.y = (int)((unsigned)h[2] | ((unsigned)h[3] << 16));
    o.z = (int)((unsigned)h[4] | ((unsigned)h[5] << 16));
    o.w = (int)((unsigned)h[6] | ((unsigned)h[7] << 16));
    ws[fid] = o;
}

// ---------------- serial 16-step recurrence (one layer) --------------------
template<int LAYER>
__device__ __forceinline__ void serial16(
    int w, int lane, int lk, int lm,
    const int4* __restrict__ ws,
    int4 (&Wlo)[8][4][3][64],
    float (&xp)[TC][G4],
    unsigned short (&hist_hi)[TC+1][136], unsigned short (&hist_lo)[TC+1][136],
    unsigned short (&h1_hi)[2][HH], unsigned short (&h1_lo)[2][HH], float* h1f,
    float& c)
{
    const int FHI = LAYER ? F_WHH1_HI : F_WHH0_HI;
    const int FLO = LAYER ? F_WHH1_LO : F_WHH0_LO;
    int4 Ahi[4][4], AloR[4];
    #pragma unroll
    for (int t4 = 0; t4 < 4; ++t4){
        #pragma unroll
        for (int s = 0; s < 4; ++s)
            Ahi[t4][s] = ws[FHI + (((w*4 + t4)*4 + s) << 6) + lane];
        AloR[t4] = ws[FLO + (((w*4 + t4)*4 + 0) << 6) + lane];
    }
    #pragma unroll
    for (int t4 = 0; t4 < 4; ++t4){
        #pragma unroll
        for (int s = 0; s < 4; ++s) KEEP4I(Ahi[t4][s]);
        KEEP4I(AloR[t4]);
    }
    const int gsel = lm >> 2;                    // this lane's gate (0..3)
    const int usel = lm & 3;
    const int u    = w*16 + lk*4 + usel;         // unit owned (c replicated x4)
    const int xpr  = gsel*128 + w*16 + lk*4 + usel;
    const int base = lane & 0x33;                // zero the gate bits [3:2]
    const bool writer = (gsel == 0);
    const bool is_g   = (gsel == 2);

    #pragma unroll 1
    for (int t = 0; t < TC; ++t){
        const int4* hh = LAYER ? (const int4*)&h1_hi[t&1][0] : (const int4*)&hist_hi[t][0];
        const int4* hl = LAYER ? (const int4*)&h1_lo[t&1][0] : (const int4*)&hist_lo[t][0];
        float xpv = xp[t][xpr];                  // prefetch: independent of MFMAs
        f32x4 acc[4];
        #pragma unroll
        for (int t4 = 0; t4 < 4; ++t4) acc[t4] = (f32x4){0.f,0.f,0.f,0.f};
        #pragma unroll
        for (int s = 0; s < 4; ++s){
            // slice-top loads: B operands + this slice's lo-weight frags
            bf16x8 bh = __builtin_bit_cast(bf16x8, hh[4*s + lk]);
            bf16x8 bl = __builtin_bit_cast(bf16x8, hl[4*s + lk]);
            int4 al[4];
            #pragma unroll
            for (int t4 = 0; t4 < 4; ++t4)
                al[t4] = (s == 0) ? AloR[t4] : Wlo[w][t4][s-1][lane];
            // term-major: same-acc distance 4 (> dep latency)
            #pragma unroll
            for (int t4 = 0; t4 < 4; ++t4) acc[t4] = mfma_(Ahi[t4][s], bh, acc[t4]);
            #pragma unroll
            for (int t4 = 0; t4 < 4; ++t4) acc[t4] = mfma_(Ahi[t4][s], bl, acc[t4]);
            #pragma unroll
            for (int t4 = 0; t4 < 4; ++t4) acc[t4] = mfma_(al[t4],     bh, acc[t4]);
            __builtin_amdgcn_sched_barrier(0);  // cap cross-slice hoisting
        }
        // 1 activation per lane: acc[gsel][usel] via static cndmask tree
        float y;
        {
            f32x4 p01 = (gsel & 1) ? acc[1] : acc[0];
            f32x4 p23 = (gsel & 1) ? acc[3] : acc[2];
            f32x4 ps  = (gsel & 2) ? p23 : p01;
            float v01 = (usel & 1) ? ps[1] : ps[0];
            float v23 = (usel & 1) ? ps[3] : ps[2];
            float v   = (usel & 2) ? v23 : v01;
            float pre = v + xpv;
            float z   = tanh_f(is_g ? pre : 0.5f*pre);
            y = is_g ? z : 0.5f*z + 0.5f;        // sigm via tanh
        }
        // wave-local gate gather: unit u's i,f,g,o sit 4 lanes apart
        float gi = __shfl(y, base);
        float gf = __shfl(y, base | 4);
        float gg = __shfl(y, base | 8);
        float go = __shfl(y, base | 12);
        c = gf*c + gi*gg;
        float h = go * tanh_f(c);
        unsigned short hhi = f2bf(h);
        unsigned short hlo = f2bf(h - bf2f(hhi));
        if (writer){
            if (LAYER){
                h1_hi[(t+1)&1][u] = hhi; h1_lo[(t+1)&1][u] = hlo; h1f[u] = h;
            } else {
                hist_hi[t+1][u] = hhi; hist_lo[t+1][u] = hlo;
            }
        }
        __syncthreads();   // single barrier per step
    }
}

// ---------------- main persistent kernel -----------------------------------
__global__ __launch_bounds__(512, 2)
void lstm_mfma(const float* __restrict__ x,
               const float* __restrict__ bih0, const float* __restrict__ bhh0,
               const float* __restrict__ bih1, const float* __restrict__ bhh1,
               const float* __restrict__ Wlin, const float* __restrict__ blin,
               const int4* __restrict__ ws,
               float* __restrict__ out)
{
    const int b    = blockIdx.x;
    const int tid  = threadIdx.x;
    const int lane = tid & 63;
    const int w    = tid >> 6;
    const int lm   = lane & 15;
    const int lk   = lane >> 4;

    __shared__ __align__(16) int4   Wlo[8][4][3][64];           // 98,304 B
    __shared__ __align__(16) float  xp[TC][G4];                 // 32,768 B
    __shared__ __align__(16) unsigned short hist_hi[TC+1][136]; //  4,624 B
    __shared__ __align__(16) unsigned short hist_lo[TC+1][136]; //  4,624 B
    __shared__ __align__(16) unsigned short xc_hi[TC][72];      //  2,304 B
    __shared__ __align__(16) unsigned short xc_lo[TC][72];      //  2,304 B
    __shared__ __align__(16) unsigned short h1_hi[2][HH];       //    512 B
    __shared__ __align__(16) unsigned short h1_lo[2][HH];       //    512 B
    __shared__ __align__(16) float  h1f[HH];                    //    512 B
    __shared__ __align__(16) float  bias[2][G4];                //  4,096 B
    // ~150 KB -> 1 block/CU, 8 waves

    bias[0][tid] = bih0[tid] + bhh0[tid];
    bias[1][tid] = bih1[tid] + bhh1[tid];
    if (tid < HH){ hist_hi[0][tid] = 0; hist_lo[0][tid] = 0;
                   h1_hi[0][tid] = 0; h1_lo[0][tid] = 0; h1f[tid] = 0.f; }
    float c0 = 0.f, c1 = 0.f;
    const float* xb = x + (size_t)b * TSEQ * II;
    __syncthreads();

    #pragma unroll 1
    for (int ch = 0; ch < NCH; ++ch){
        // ---- A: stage x chunk as bf16 pairs; carry h0 ----
        {
            int i0 = tid, i1 = tid + 512;
            float v0 = xb[(size_t)ch*TC*II + i0];
            float v1 = xb[(size_t)ch*TC*II + i1];
            unsigned short a0 = f2bf(v0), a1 = f2bf(v1);
            xc_hi[i0>>6][i0&63] = a0; xc_lo[i0>>6][i0&63] = f2bf(v0 - bf2f(a0));
            xc_hi[i1>>6][i1&63] = a1; xc_lo[i1>>6][i1&63] = f2bf(v1 - bf2f(a1));
        }
        if (ch > 0 && tid < HH){
            hist_hi[0][tid] = hist_hi[TC][tid];
            hist_lo[0][tid] = hist_lo[TC][tid];
        }
        __syncthreads();

        // ---- B: stage Wlo<-Whh0_lo(ks1-3) + proj xp0 (K=64, B = xc pairs) ----
        {
            #pragma unroll
            for (int t4 = 0; t4 < 4; ++t4)
                #pragma unroll
                for (int s = 1; s < 4; ++s)
                    Wlo[w][t4][s-1][lane] = ws[F_WHH0_LO + (((w*4 + t4)*4 + s) << 6) + lane];

            f32x4 acc[4];
            #pragma unroll
            for (int t4 = 0; t4 < 4; ++t4) acc[t4] = (f32x4){0.f,0.f,0.f,0.f};
            #pragma unroll
            for (int s = 0; s < 2; ++s){
                int4 vh = *(const int4*)&xc_hi[lm][s*32 + lk*8];
                int4 vl = *(const int4*)&xc_lo[lm][s*32 + lk*8];
                bf16x8 bh = __builtin_bit_cast(bf16x8, vh);
                bf16x8 bl = __builtin_bit_cast(bf16x8, vl);
                int4 ah[4], al[4];
                #pragma unroll
                for (int t4 = 0; t4 < 4; ++t4){
                    ah[t4] = ws[F_WIH0_HI + (((w*4 + t4)*2 + s) << 6) + lane];
                    al[t4] = ws[F_WIH0_LO + (((w*4 + t4)*2 + s) << 6) + lane];
                }
                #pragma unroll
                for (int t4 = 0; t4 < 4; ++t4) acc[t4] = mfma_(ah[t4], bh, acc[t4]);
                #pragma unroll
                for (int t4 = 0; t4 < 4; ++t4) acc[t4] = mfma_(ah[t4], bl, acc[t4]);
                #pragma unroll
                for (int t4 = 0; t4 < 4; ++t4) acc[t4] = mfma_(al[t4], bh, acc[t4]);
                __builtin_amdgcn_sched_barrier(0);
            }
            #pragma unroll
            for (int t4 = 0; t4 < 4; ++t4){
                int rowb = t4*128 + w*16 + lk*4;      // gate-major row base
                *(f32x4*)&xp[lm][rowb] = acc[t4] + *(const f32x4*)&bias[0][rowb];
            }
        }
        __syncthreads();

        // ---- C: layer0 serial 16 steps ----
        serial16<0>(w, lane, lk, lm, ws, Wlo, xp, hist_hi, hist_lo,
                    h1_hi, h1_lo, h1f, c0);

        // ---- D: stage Wlo<-Whh1_lo(ks1-3) + proj xp1 (K=128, B = hist pairs) ----
        {
            #pragma unroll
            for (int t4 = 0; t4 < 4; ++t4)
                #pragma unroll
                for (int s = 1; s < 4; ++s)
                    Wlo[w][t4][s-1][lane] = ws[F_WHH1_LO + (((w*4 + t4)*4 + s) << 6) + lane];

            f32x4 acc[4];
            #pragma unroll
            for (int t4 = 0; t4 < 4; ++t4) acc[t4] = (f32x4){0.f,0.f,0.f,0.f};
            #pragma unroll
            for (int s = 0; s < 4; ++s){
                int4 vh = *(const int4*)&hist_hi[lm + 1][s*32 + lk*8];
                int4 vl = *(const int4*)&hist_lo[lm + 1][s*32 + lk*8];
                bf16x8 bh = __builtin_bit_cast(bf16x8, vh);
                bf16x8 bl = __builtin_bit_cast(bf16x8, vl);
                int4 ah[4], al[4];
                #pragma unroll
                for (int t4 = 0; t4 < 4; ++t4){
                    ah[t4] = ws[F_WIH1_HI + (((w*4 + t4)*4 + s) << 6) + lane];
                    al[t4] = ws[F_WIH1_LO + (((w*4 + t4)*4 + s) << 6) + lane];
                }
                #pragma unroll
                for (int t4 = 0; t4 < 4; ++t4) acc[t4] = mfma_(ah[t4], bh, acc[t4]);
                #pragma unroll
                for (int t4 = 0; t4 < 4; ++t4) acc[t4] = mfma_(ah[t4], bl, acc[t4]);
                #pragma unroll
                for (int t4 = 0; t4 < 4; ++t4) acc[t4] = mfma_(al[t4], bh, acc[t4]);
                __builtin_amdgcn_sched_barrier(0);
            }
            #pragma unroll
            for (int t4 = 0; t4 < 4; ++t4){
                int rowb = t4*128 + w*16 + lk*4;
                *(f32x4*)&xp[lm][rowb] = acc[t4] + *(const f32x4*)&bias[1][rowb];
            }
        }
        __syncthreads();

        // ---- E: layer1 serial 16 steps ----
        serial16<1>(w, lane, lk, lm, ws, Wlo, xp, hist_hi, hist_lo,
                    h1_hi, h1_lo, h1f, c1);
    }

    // ---- final linear: out[b] = h1 . Wlin[0,:] + blin ----
    if (tid < 64){
        float s = h1f[tid]*Wlin[tid] + h1f[tid+64]*Wlin[tid+64];
        #pragma unroll
        for (int off = 32; off; off >>= 1) s += __shfl_down(s, off);
        if (tid == 0) out[b] = s + blin[0];
    }
}

extern "C" void kernel_launch(void* const* d_in, const int* in_sizes, int n_in,
                              void* d_out, int out_size, void* d_ws, size_t ws_size,
                              hipStream_t stream)
{
    const float* x    = (const float*)d_in[0];
    const float* Wih0 = (const float*)d_in[1];
    const float* Whh0 = (const float*)d_in[2];
    const float* bih0 = (const float*)d_in[3];
    const float* bhh0 = (const float*)d_in[4];
    const float* Wih1 = (const float*)d_in[5];
    const float* Whh1 = (const float*)d_in[6];
    const float* bih1 = (const float*)d_in[7];
    const float* bhh1 = (const float*)d_in[8];
    const float* Wlin = (const float*)d_in[9];
    const float* blin = (const float*)d_in[10];
    int4* ws = (int4*)d_ws;   // requires ws_size >= 917,504 B

    hipLaunchKernelGGL(pack_w, dim3(F_TOTAL/256), dim3(256), 0, stream,
                       Wih0, Whh0, Wih1, Whh1, ws);
    hipLaunchKernelGGL(lstm_mfma, dim3(NB), dim3(512), 0, stream,
                       x, bih0, bhh0, bih1, bhh1, Wlin, blin, ws, (float*)d_out);
}

// Round 11
// 2130.735 us; speedup vs baseline: 2.1469x; 2.1469x over previous
//
#include <hip/hip_runtime.h>

// LSTM 2-layer fused persistent kernel — MFMA fp16 2-term split, fp32 I/O.
// 256 blocks (1 batch row / CU) x 512 threads, __launch_bounds__(512,2) (the
// only proven no-spill regime: 128-VGPR grant).
// R11 change vs R10: drop the wlo*h MFMA term entirely. Weights are single
// fp16 (RNE, rel err 2^-12); h/x kept as fp16 hi + SCALED lo (lo*2^10 stays
// in fp16 normal range); term2 accumulates in a separate accL, combined as
// acc + accL*2^-10 in f32. Justified by the measured anchor: 3-term bf16
// (dW~2^-17) -> absmax 1.2e-7 = no error amplification; dW 2^-12 predicts
// ~4e-6 << 9.3e-4 threshold.
// Wins: 48->32 MFMA/wave/step in 8 independent 4-deep chains (R10 showed
// 14-16cyc/MFMA = scheduler serialized the 4x12 chains); ds_reads 20->8
// per step (Wlo LDS + its 12 reads deleted); LDS 151KB->~51KB; tanh via
// v_rcp_f32 instead of fp32 div sequence.
// Gate-major ownership (R9): wave w owns {i,f,g,o} x units [16w,16w+16);
// c-update wave-local via 4 __shfl; h ping-pong; 1 barrier/step.
// Fragment maps (m89-verified): A[row=lane&15, k=(lane>>4)*8+j],
// B[k=(lane>>4)*8+j, col=lane&15], D[col=lane&15, row=(lane>>4)*4+reg];
// B column-replicated -> every lane holds valid D rows.
// d_ws requirement: 458,752 B.

typedef __attribute__((ext_vector_type(4))) float f32x4;
typedef _Float16 f16x8 __attribute__((ext_vector_type(8)));

#define NB   256
#define TSEQ 1024
#define II   64
#define HH   128
#define G4   512
#define TC   16
#define NCH  (TSEQ/TC)
#define SCL  0.0009765625f   // 2^-10
#define SCLI 1024.f          // 2^10

// d_ws frag regions (16B units). idx = region + ((w*4+t4)*NKS+s)*64 + lane.
#define F_WHH0  0
#define F_WHH1  8192
#define F_WIH1  16384
#define F_WIH0  24576
#define F_TOTAL 28672   // *16B = 458,752 B

#define KEEP4I(v) asm volatile("" : "+v"((v).x), "+v"((v).y), "+v"((v).z), "+v"((v).w))

__device__ __forceinline__ float tanh_f(float x){
    float ax = fabsf(x);
    float e  = __expf(2.f*ax);
    float t  = 1.f - 2.f*__builtin_amdgcn_rcpf(e + 1.f);  // no div sequence
    return copysignf(t, x);
}
__device__ __forceinline__ f32x4 mfma16(int4 a, f16x8 b, f32x4 c){
    return __builtin_amdgcn_mfma_f32_16x16x32_f16(
        __builtin_bit_cast(f16x8, a), b, c, 0, 0, 0);
}
__device__ __forceinline__ f16x8 ldb(const _Float16* p){
    return __builtin_bit_cast(f16x8, *(const int4*)p);
}

// ---------------- pack kernel: fp32 weights -> fp16 A-fragments ------------
// Gate-major row map: fragment (w, t4, s, lane) holds
// row = t4*128 + w*16 + (lane&15), k = s*32 + (lane>>4)*8 + j.
__global__ void pack_w(const float* __restrict__ Wih0, const float* __restrict__ Whh0,
                       const float* __restrict__ Wih1, const float* __restrict__ Whh1,
                       int4* __restrict__ ws)
{
    int fid = blockIdx.x * 256 + threadIdx.x;
    if (fid >= F_TOTAL) return;
    const float* src; int nks; int rb;
    if (fid < F_WHH1)      { src = Whh0; nks = 4; rb = fid; }
    else if (fid < F_WIH1) { src = Whh1; nks = 4; rb = fid - F_WHH1; }
    else if (fid < F_WIH0) { src = Wih1; nks = 4; rb = fid - F_WIH1; }
    else                   { src = Wih0; nks = 2; rb = fid - F_WIH0; }
    int lane = rb & 63;
    int rem  = rb >> 6;
    int s    = rem % nks;
    int t    = (rem / nks) & 3;
    int w    = rem / (nks * 4);
    int row  = t * 128 + w * 16 + (lane & 15);   // gate-major
    int K    = nks * 32;
    int k0   = s * 32 + (lane >> 4) * 8;
    const float* p = src + (size_t)row * K + k0;
    unsigned short us[8];
    #pragma unroll
    for (int j = 0; j < 8; ++j)
        us[j] = __builtin_bit_cast(unsigned short, (_Float16)p[j]);  // RNE
    int4 o;
    o.x = (int)((unsigned)us[0] | ((unsigned)us[1] << 16));
    o.y = (int)((unsigned)us[2] | ((unsigned)us[3] << 16));
    o.z = (int)((unsigned)us[4] | ((unsigned)us[5] << 16));
    o.w = (int)((unsigned)us[6] | ((unsigned)us[7] << 16));
    ws[fid] = o;
}

// ---------------- serial 16-step recurrence (one layer) --------------------
template<int LAYER>
__device__ __forceinline__ void serial16(
    int w, int lane, int lk, int lm,
    const int4* __restrict__ ws,
    float (&xp)[TC][G4],
    _Float16 (&hist_hi)[TC+1][136], _Float16 (&hist_lo)[TC+1][136],
    _Float16 (&h1_hi)[2][HH], _Float16 (&h1_lo)[2][HH], float* h1f,
    float& c)
{
    const int F = LAYER ? F_WHH1 : F_WHH0;
    int4 Ahi[4][4];
    #pragma unroll
    for (int t4 = 0; t4 < 4; ++t4)
        #pragma unroll
        for (int s = 0; s < 4; ++s)
            Ahi[t4][s] = ws[F + (((w*4 + t4)*4 + s) << 6) + lane];
    #pragma unroll
    for (int t4 = 0; t4 < 4; ++t4)
        #pragma unroll
        for (int s = 0; s < 4; ++s) KEEP4I(Ahi[t4][s]);

    const int gsel = lm >> 2;                    // this lane's gate (0..3)
    const int usel = lm & 3;
    const int u    = w*16 + lk*4 + usel;         // unit owned (c replicated x4)
    const int xpr  = gsel*128 + w*16 + lk*4 + usel;
    const int base = lane & 0x33;                // zero the gate bits [3:2]
    const bool writer = (gsel == 0);
    const bool is_g   = (gsel == 2);

    #pragma unroll 1
    for (int t = 0; t < TC; ++t){
        const _Float16* hhp = LAYER ? &h1_hi[t&1][0] : &hist_hi[t][0];
        const _Float16* hlp = LAYER ? &h1_lo[t&1][0] : &hist_lo[t][0];
        float xpv = xp[t][xpr];                  // step-independent prefetch
        f32x4 acc[4], accL[4];
        #pragma unroll
        for (int t4 = 0; t4 < 4; ++t4){
            acc[t4]  = (f32x4){0.f,0.f,0.f,0.f};
            accL[t4] = (f32x4){0.f,0.f,0.f,0.f};
        }
        #pragma unroll
        for (int s = 0; s < 4; ++s){
            f16x8 bh = ldb(&hhp[s*32 + lk*8]);
            f16x8 bl = ldb(&hlp[s*32 + lk*8]);
            // 8 independent chains: acc[0..3] and accL[0..3]
            #pragma unroll
            for (int t4 = 0; t4 < 4; ++t4) acc[t4]  = mfma16(Ahi[t4][s], bh, acc[t4]);
            #pragma unroll
            for (int t4 = 0; t4 < 4; ++t4) accL[t4] = mfma16(Ahi[t4][s], bl, accL[t4]);
            if (s == 1) __builtin_amdgcn_sched_barrier(0);  // cap hoist depth
        }
        // combine lo-term, then 1 activation per lane via static cndmask tree
        f32x4 cmb[4];
        #pragma unroll
        for (int t4 = 0; t4 < 4; ++t4) cmb[t4] = acc[t4] + accL[t4]*SCL;
        float y;
        {
            f32x4 p01 = (gsel & 1) ? cmb[1] : cmb[0];
            f32x4 p23 = (gsel & 1) ? cmb[3] : cmb[2];
            f32x4 ps  = (gsel & 2) ? p23 : p01;
            float v01 = (usel & 1) ? ps[1] : ps[0];
            float v23 = (usel & 1) ? ps[3] : ps[2];
            float v   = (usel & 2) ? v23 : v01;
            float pre = v + xpv;
            float z   = tanh_f(is_g ? pre : 0.5f*pre);
            y = is_g ? z : 0.5f*z + 0.5f;        // sigm via tanh
        }
        // wave-local gate gather: unit u's i,f,g,o sit 4 lanes apart
        float gi = __shfl(y, base);
        float gf = __shfl(y, base | 4);
        float gg = __shfl(y, base | 8);
        float go = __shfl(y, base | 12);
        c = gf*c + gi*gg;
        float h = go * tanh_f(c);
        _Float16 hf = (_Float16)h;
        _Float16 hl = (_Float16)((h - (float)hf) * SCLI);
        if (writer){
            if (LAYER){
                h1_hi[(t+1)&1][u] = hf; h1_lo[(t+1)&1][u] = hl; h1f[u] = h;
            } else {
                hist_hi[t+1][u] = hf; hist_lo[t+1][u] = hl;
            }
        }
        __syncthreads();   // single barrier per step
    }
}

// ---------------- main persistent kernel -----------------------------------
__global__ __launch_bounds__(512, 2)
void lstm_mfma(const float* __restrict__ x,
               const float* __restrict__ bih0, const float* __restrict__ bhh0,
               const float* __restrict__ bih1, const float* __restrict__ bhh1,
               const float* __restrict__ Wlin, const float* __restrict__ blin,
               const int4* __restrict__ ws,
               float* __restrict__ out)
{
    const int b    = blockIdx.x;
    const int tid  = threadIdx.x;
    const int lane = tid & 63;
    const int w    = tid >> 6;
    const int lm   = lane & 15;
    const int lk   = lane >> 4;

    __shared__ __align__(16) float    xp[TC][G4];            // 32,768 B
    __shared__ __align__(16) _Float16 hist_hi[TC+1][136];    //  4,624 B
    __shared__ __align__(16) _Float16 hist_lo[TC+1][136];    //  4,624 B
    __shared__ __align__(16) _Float16 xc_hi[TC][72];         //  2,304 B
    __shared__ __align__(16) _Float16 xc_lo[TC][72];         //  2,304 B
    __shared__ __align__(16) _Float16 h1_hi[2][HH];          //    512 B
    __shared__ __align__(16) _Float16 h1_lo[2][HH];          //    512 B
    __shared__ __align__(16) float    h1f[HH];               //    512 B
    __shared__ __align__(16) float    bias[2][G4];           //  4,096 B
    // ~52 KB

    bias[0][tid] = bih0[tid] + bhh0[tid];
    bias[1][tid] = bih1[tid] + bhh1[tid];
    if (tid < HH){ hist_hi[0][tid] = (_Float16)0.f; hist_lo[0][tid] = (_Float16)0.f;
                   h1_hi[0][tid] = (_Float16)0.f; h1_lo[0][tid] = (_Float16)0.f;
                   h1f[tid] = 0.f; }
    float c0 = 0.f, c1 = 0.f;
    const float* xb = x + (size_t)b * TSEQ * II;
    __syncthreads();

    #pragma unroll 1
    for (int ch = 0; ch < NCH; ++ch){
        // ---- A: stage x chunk as fp16 hi + scaled lo; carry h0 ----
        {
            int i0 = tid, i1 = tid + 512;
            float v0 = xb[(size_t)ch*TC*II + i0];
            float v1 = xb[(size_t)ch*TC*II + i1];
            _Float16 a0 = (_Float16)v0, a1 = (_Float16)v1;
            xc_hi[i0>>6][i0&63] = a0; xc_lo[i0>>6][i0&63] = (_Float16)((v0 - (float)a0)*SCLI);
            xc_hi[i1>>6][i1&63] = a1; xc_lo[i1>>6][i1&63] = (_Float16)((v1 - (float)a1)*SCLI);
        }
        if (ch > 0 && tid < HH){
            hist_hi[0][tid] = hist_hi[TC][tid];
            hist_lo[0][tid] = hist_lo[TC][tid];
        }
        __syncthreads();

        // ---- B: proj xp0 (K=64, B = xc fp16 pairs) ----
        {
            f32x4 acc[4], accL[4];
            #pragma unroll
            for (int t4 = 0; t4 < 4; ++t4){
                acc[t4]  = (f32x4){0.f,0.f,0.f,0.f};
                accL[t4] = (f32x4){0.f,0.f,0.f,0.f};
            }
            #pragma unroll
            for (int s = 0; s < 2; ++s){
                f16x8 bh = ldb(&xc_hi[lm][s*32 + lk*8]);
                f16x8 bl = ldb(&xc_lo[lm][s*32 + lk*8]);
                int4 ah[4];
                #pragma unroll
                for (int t4 = 0; t4 < 4; ++t4)
                    ah[t4] = ws[F_WIH0 + (((w*4 + t4)*2 + s) << 6) + lane];
                #pragma unroll
                for (int t4 = 0; t4 < 4; ++t4) acc[t4]  = mfma16(ah[t4], bh, acc[t4]);
                #pragma unroll
                for (int t4 = 0; t4 < 4; ++t4) accL[t4] = mfma16(ah[t4], bl, accL[t4]);
            }
            #pragma unroll
            for (int t4 = 0; t4 < 4; ++t4){
                int rowb = t4*128 + w*16 + lk*4;      // gate-major row base
                f32x4 cmb = acc[t4] + accL[t4]*SCL;
                *(f32x4*)&xp[lm][rowb] = cmb + *(const f32x4*)&bias[0][rowb];
            }
        }
        __syncthreads();

        // ---- C: layer0 serial 16 steps ----
        serial16<0>(w, lane, lk, lm, ws, xp, hist_hi, hist_lo,
                    h1_hi, h1_lo, h1f, c0);

        // ---- D: proj xp1 (K=128, B = hist fp16 pairs) ----
        {
            f32x4 acc[4], accL[4];
            #pragma unroll
            for (int t4 = 0; t4 < 4; ++t4){
                acc[t4]  = (f32x4){0.f,0.f,0.f,0.f};
                accL[t4] = (f32x4){0.f,0.f,0.f,0.f};
            }
            #pragma unroll
            for (int s = 0; s < 4; ++s){
                f16x8 bh = ldb(&hist_hi[lm + 1][s*32 + lk*8]);
                f16x8 bl = ldb(&hist_lo[lm + 1][s*32 + lk*8]);
                int4 ah[4];
                #pragma unroll
                for (int t4 = 0; t4 < 4; ++t4)
                    ah[t4] = ws[F_WIH1 + (((w*4 + t4)*4 + s) << 6) + lane];
                #pragma unroll
                for (int t4 = 0; t4 < 4; ++t4) acc[t4]  = mfma16(ah[t4], bh, acc[t4]);
                #pragma unroll
                for (int t4 = 0; t4 < 4; ++t4) accL[t4] = mfma16(ah[t4], bl, accL[t4]);
                if (s == 1) __builtin_amdgcn_sched_barrier(0);
            }
            #pragma unroll
            for (int t4 = 0; t4 < 4; ++t4){
                int rowb = t4*128 + w*16 + lk*4;
                f32x4 cmb = acc[t4] + accL[t4]*SCL;
                *(f32x4*)&xp[lm][rowb] = cmb + *(const f32x4*)&bias[1][rowb];
            }
        }
        __syncthreads();

        // ---- E: layer1 serial 16 steps ----
        serial16<1>(w, lane, lk, lm, ws, xp, hist_hi, hist_lo,
                    h1_hi, h1_lo, h1f, c1);
    }

    // ---- final linear: out[b] = h1 . Wlin[0,:] + blin ----
    if (tid < 64){
        float s = h1f[tid]*Wlin[tid] + h1f[tid+64]*Wlin[tid+64];
        #pragma unroll
        for (int off = 32; off; off >>= 1) s += __shfl_down(s, off);
        if (tid == 0) out[b] = s + blin[0];
    }
}

extern "C" void kernel_launch(void* const* d_in, const int* in_sizes, int n_in,
                              void* d_out, int out_size, void* d_ws, size_t ws_size,
                              hipStream_t stream)
{
    const float* x    = (const float*)d_in[0];
    const float* Wih0 = (const float*)d_in[1];
    const float* Whh0 = (const float*)d_in[2];
    const float* bih0 = (const float*)d_in[3];
    const float* bhh0 = (const float*)d_in[4];
    const float* Wih1 = (const float*)d_in[5];
    const float* Whh1 = (const float*)d_in[6];
    const float* bih1 = (const float*)d_in[7];
    const float* bhh1 = (const float*)d_in[8];
    const float* Wlin = (const float*)d_in[9];
    const float* blin = (const float*)d_in[10];
    int4* ws = (int4*)d_ws;   // requires ws_size >= 458,752 B

    hipLaunchKernelGGL(pack_w, dim3(F_TOTAL/256), dim3(256), 0, stream,
                       Wih0, Whh0, Wih1, Whh1, ws);
    hipLaunchKernelGGL(lstm_mfma, dim3(NB), dim3(512), 0, stream,
                       x, bih0, bhh0, bih1, bhh1, Wlin, blin, ws, (float*)d_out);
}